// Round 1
// baseline (241.483 us; speedup 1.0000x reference)
//
#include <hip/hip_runtime.h>
#include <cstdint>
#include <cstddef>

#define S_LEN 2048
#define NH 16
#define HD 64
#define DM 1024
#define WIN 1024

typedef unsigned short u16;
typedef __attribute__((ext_vector_type(8))) short bf16x8;
typedef __attribute__((ext_vector_type(4))) float f32x4;
typedef __attribute__((ext_vector_type(4))) u16 u16x4;

__device__ inline u16 f2b(float f) {
  union { float f; uint32_t u; } x; x.f = f;
  uint32_t r = x.u + 0x7FFFu + ((x.u >> 16) & 1u);
  return (u16)(r >> 16);
}

// ---------------- f32 -> bf16 conversion ----------------
__global__ __launch_bounds__(256) void cvt_kernel(const float* __restrict__ src,
                                                  u16* __restrict__ dst, int n) {
  int i = (blockIdx.x * 256 + threadIdx.x) * 4;
  if (i >= n) return;
  f32x4 v = *(const f32x4*)(src + i);
  u16x4 o;
  o[0] = f2b(v[0]); o[1] = f2b(v[1]); o[2] = f2b(v[2]); o[3] = f2b(v[3]);
  *(u16x4*)(dst + i) = o;
}

// ---------------- bf16 NT GEMM: C = A * B^T + bias ----------------
// A: [M][K] bf16 row-major, B: [N][K] bf16 row-major.
// EPI 0: write f32 to outF[row*N+col]
// EPI 1: write bf16 reshaped to outQ[((b*NH+h)*S_LEN+s)*HD+d], row=(b,s), col=(h,d)
template<int EPI>
__global__ __launch_bounds__(512)
void gemm_nt(const u16* __restrict__ A, const u16* __restrict__ B,
             const float* __restrict__ bias, float* __restrict__ outF,
             u16* __restrict__ outQ, int M, int N, int K) {
  __shared__ u16 As[128 * 32];
  __shared__ u16 Bs[128 * 32];
  const int t = threadIdx.x;
  const int lane = t & 63, wid = t >> 6;
  const int l15 = lane & 15, l4 = lane >> 4;
  const int wr = wid >> 2, wc = wid & 3;        // 2 x 4 wave grid, wave tile 64x32
  const int bm = blockIdx.x * 128, bn = blockIdx.y * 128;
  const int sr = t >> 2, sc = (t & 3) << 3;     // staging: row t/4, col (t%4)*8
  const u16* Ag = A + (size_t)(bm + sr) * K + sc;
  const u16* Bg = B + (size_t)(bn + sr) * K + sc;
  f32x4 acc[4][2];
#pragma unroll
  for (int i = 0; i < 4; i++)
#pragma unroll
    for (int j = 0; j < 2; j++) acc[i][j] = (f32x4){0.f, 0.f, 0.f, 0.f};

  for (int kb = 0; kb < K; kb += 32) {
    __syncthreads();
    *(bf16x8*)&As[sr * 32 + sc] = *(const bf16x8*)(Ag + kb);
    *(bf16x8*)&Bs[sr * 32 + sc] = *(const bf16x8*)(Bg + kb);
    __syncthreads();
    bf16x8 af[4], bq[2];
#pragma unroll
    for (int mi = 0; mi < 4; mi++)
      af[mi] = *(bf16x8*)&As[(wr * 64 + mi * 16 + l15) * 32 + l4 * 8];
#pragma unroll
    for (int ni = 0; ni < 2; ni++)
      bq[ni] = *(bf16x8*)&Bs[(wc * 32 + ni * 16 + l15) * 32 + l4 * 8];
#pragma unroll
    for (int mi = 0; mi < 4; mi++)
#pragma unroll
      for (int ni = 0; ni < 2; ni++)
        acc[mi][ni] = __builtin_amdgcn_mfma_f32_16x16x32_bf16(af[mi], bq[ni], acc[mi][ni], 0, 0, 0);
  }

#pragma unroll
  for (int mi = 0; mi < 4; mi++) {
#pragma unroll
    for (int ni = 0; ni < 2; ni++) {
#pragma unroll
      for (int r = 0; r < 4; r++) {
        int row = bm + wr * 64 + mi * 16 + l4 * 4 + r;
        int col = bn + wc * 32 + ni * 16 + l15;
        float v = acc[mi][ni][r] + bias[col];
        if (EPI == 0) {
          outF[(size_t)row * N + col] = v;
        } else {
          int b = row >> 11, s = row & (S_LEN - 1);
          int h = col >> 6, d = col & (HD - 1);
          outQ[(((size_t)b * NH + h) * S_LEN + s) * HD + d] = f2b(v);
        }
      }
    }
  }
}

// ---------------- V transpose: [BH][S][64] -> [BH][64][S] ----------------
__global__ __launch_bounds__(256)
void transpose_v(const u16* __restrict__ V, u16* __restrict__ Vt) {
  const int bh = blockIdx.y;
  const int s0 = blockIdx.x * 64;
  __shared__ u16 tile[64][72];
  const int t = threadIdx.x;
  const u16* src = V + ((size_t)bh * S_LEN + s0) * HD;
#pragma unroll
  for (int i = 0; i < 2; i++) {
    int e = t * 8 + i * 2048;
    int r = e >> 6, c = e & 63;
    *(bf16x8*)&tile[r][c] = *(const bf16x8*)(src + e);
  }
  __syncthreads();
  u16* dst = Vt + (size_t)bh * HD * S_LEN + s0;
#pragma unroll
  for (int i = 0; i < 2; i++) {
    int e = t * 8 + i * 2048;
    int d = e >> 6, s = e & 63;
    bf16x8 tmp;
#pragma unroll
    for (int j = 0; j < 8; j++) tmp[j] = (short)tile[s + j][d];
    *(bf16x8*)&dst[(size_t)d * S_LEN + s] = tmp;
  }
}

// ---------------- sliding-window attention with ALiBi ----------------
// Q,K: [BH][S][64] bf16; Vt: [BH][64][S] bf16; out attn: [B*S][1024] bf16
__global__ __launch_bounds__(256)
void attn_kernel(const u16* __restrict__ Q, const u16* __restrict__ Kg,
                 const u16* __restrict__ Vt, u16* __restrict__ attn) {
  const int qt = blockIdx.x;   // 32 query tiles of 64
  const int h = blockIdx.y;    // 16 heads
  const int b = blockIdx.z;    // 2 batches
  const int t = threadIdx.x;
  const int lane = t & 63, wid = t >> 6;
  const int l15 = lane & 15, l4 = lane >> 4;
  const int q0 = qt * 64;
  const int qw = q0 + wid * 16;
  const size_t bh = (size_t)b * NH + h;
  const u16* Qp = Q + bh * S_LEN * HD;
  const u16* Kp = Kg + bh * S_LEN * HD;
  const u16* Vp = Vt + bh * HD * S_LEN;
  __shared__ u16 P[4][16 * 32];

  bf16x8 qa[2];
#pragma unroll
  for (int ks = 0; ks < 2; ks++)
    qa[ks] = *(const bf16x8*)(Qp + (size_t)(qw + l15) * HD + ks * 32 + l4 * 8);

  const float slope = exp2f(-0.5f * (float)(h + 1));
  float m[4], l[4];
  f32x4 O[4];
#pragma unroll
  for (int r = 0; r < 4; r++) { m[r] = -3e38f; l[r] = 0.f; }
#pragma unroll
  for (int d = 0; d < 4; d++) O[d] = (f32x4){0.f, 0.f, 0.f, 0.f};

  int kb_lo = q0 - (WIN - 1);
  if (kb_lo < 0) kb_lo = 0;
  kb_lo &= ~31;
  const int kb_hi = q0 + 32;

  for (int kb = kb_lo; kb <= kb_hi; kb += 32) {
    // ---- scores: QK^T for 16 q rows x 32 keys ----
    f32x4 sf[2];
#pragma unroll
    for (int f = 0; f < 2; f++) {
      sf[f] = (f32x4){0.f, 0.f, 0.f, 0.f};
#pragma unroll
      for (int ks = 0; ks < 2; ks++) {
        bf16x8 kf = *(const bf16x8*)(Kp + (size_t)(kb + f * 16 + l15) * HD + ks * 32 + l4 * 8);
        sf[f] = __builtin_amdgcn_mfma_f32_16x16x32_bf16(qa[ks], kf, sf[f], 0, 0, 0);
      }
    }
    // ---- scale + alibi + mask ----
    float sv[2][4], rmax[4];
#pragma unroll
    for (int r = 0; r < 4; r++) rmax[r] = -3e38f;
#pragma unroll
    for (int f = 0; f < 2; f++) {
      int kcol = kb + f * 16 + l15;
#pragma unroll
      for (int r = 0; r < 4; r++) {
        int qrow = qw + l4 * 4 + r;
        float s = sf[f][r] * 0.125f + slope * (float)(kcol - qrow);
        bool masked = (kcol > qrow) || (kcol <= qrow - WIN);
        s = masked ? -3e38f : s;
        sv[f][r] = s;
        rmax[r] = fmaxf(rmax[r], s);
      }
    }
#pragma unroll
    for (int r = 0; r < 4; r++) {
#pragma unroll
      for (int off = 1; off < 16; off <<= 1)
        rmax[r] = fmaxf(rmax[r], __shfl_xor(rmax[r], off, 64));
    }
    float sc[4];
#pragma unroll
    for (int r = 0; r < 4; r++) {
      float mn = fmaxf(fmaxf(m[r], rmax[r]), -1e30f);
      sc[r] = __expf(m[r] - mn);
      m[r] = mn;
    }
    float p[2][4];
#pragma unroll
    for (int f = 0; f < 2; f++)
#pragma unroll
      for (int r = 0; r < 4; r++)
        p[f][r] = __expf(sv[f][r] - m[r]);
#pragma unroll
    for (int r = 0; r < 4; r++) {
      float s2 = p[0][r] + p[1][r];
#pragma unroll
      for (int off = 1; off < 16; off <<= 1)
        s2 += __shfl_xor(s2, off, 64);
      l[r] = l[r] * sc[r] + s2;
    }
    // ---- P -> bf16 A-frag via per-wave LDS transpose ----
#pragma unroll
    for (int f = 0; f < 2; f++)
#pragma unroll
      for (int r = 0; r < 4; r++)
        P[wid][(l4 * 4 + r) * 32 + f * 16 + l15] = f2b(p[f][r]);
    __syncthreads();  // drains LDS writes (per-wave region; ordering only)
    bf16x8 pa = *(bf16x8*)&P[wid][l15 * 32 + l4 * 8];
    // ---- rescale O, then PV ----
#pragma unroll
    for (int d = 0; d < 4; d++)
#pragma unroll
      for (int r = 0; r < 4; r++) O[d][r] *= sc[r];
#pragma unroll
    for (int d = 0; d < 4; d++) {
      bf16x8 vf = *(const bf16x8*)(Vp + (size_t)(d * 16 + l15) * S_LEN + kb + l4 * 8);
      O[d] = __builtin_amdgcn_mfma_f32_16x16x32_bf16(pa, vf, O[d], 0, 0, 0);
    }
    __syncthreads();  // protect P before next iteration's writes
  }

  float inv[4];
#pragma unroll
  for (int r = 0; r < 4; r++) inv[r] = 1.f / l[r];
  u16* op = attn + (size_t)b * S_LEN * DM;
#pragma unroll
  for (int d = 0; d < 4; d++)
#pragma unroll
    for (int r = 0; r < 4; r++) {
      int s = qw + l4 * 4 + r;
      op[(size_t)s * DM + h * HD + d * 16 + l15] = f2b(O[d][r] * inv[r]);
    }
}

// ---------------- launch ----------------
extern "C" void kernel_launch(void* const* d_in, const int* in_sizes, int n_in,
                              void* d_out, int out_size, void* d_ws, size_t ws_size,
                              hipStream_t stream) {
  const float* x  = (const float*)d_in[0];
  const float* wq = (const float*)d_in[1];
  const float* bq = (const float*)d_in[2];
  const float* wk = (const float*)d_in[3];
  const float* bk = (const float*)d_in[4];
  const float* wv = (const float*)d_in[5];
  const float* bv = (const float*)d_in[6];
  const float* wo = (const float*)d_in[7];
  const float* bo = (const float*)d_in[8];

  char* ws = (char*)d_ws;
  u16* xb  = (u16*)(ws);                    // 8 MB   [4096][1024]
  u16* wqb = (u16*)(ws + 8388608);          // 2 MB
  u16* wkb = (u16*)(ws + 10485760);         // 2 MB
  u16* wvb = (u16*)(ws + 12582912);         // 2 MB
  u16* wob = (u16*)(ws + 14680064);         // 2 MB
  u16* Qb  = (u16*)(ws + 16777216);         // 8 MB   [BH][S][64]
  u16* Kb  = (u16*)(ws + 25165824);         // 8 MB
  u16* Vb  = (u16*)(ws + 33554432);         // 8 MB
  u16* Vtb = (u16*)(ws + 41943040);         // 8 MB   [BH][64][S]
  u16* Ab  = (u16*)(ws + 50331648);         // 8 MB   [B*S][1024]

  const int M = 4096, N = DM, K = DM;

  cvt_kernel<<<dim3(4096), dim3(256), 0, stream>>>(x, xb, 4194304);
  cvt_kernel<<<dim3(1024), dim3(256), 0, stream>>>(wq, wqb, 1048576);
  cvt_kernel<<<dim3(1024), dim3(256), 0, stream>>>(wk, wkb, 1048576);
  cvt_kernel<<<dim3(1024), dim3(256), 0, stream>>>(wv, wvb, 1048576);
  cvt_kernel<<<dim3(1024), dim3(256), 0, stream>>>(wo, wob, 1048576);

  gemm_nt<1><<<dim3(32, 8), dim3(512), 0, stream>>>(xb, wqb, bq, nullptr, Qb, M, N, K);
  gemm_nt<1><<<dim3(32, 8), dim3(512), 0, stream>>>(xb, wkb, bk, nullptr, Kb, M, N, K);
  gemm_nt<1><<<dim3(32, 8), dim3(512), 0, stream>>>(xb, wvb, bv, nullptr, Vb, M, N, K);

  transpose_v<<<dim3(32, 32), dim3(256), 0, stream>>>(Vb, Vtb);

  attn_kernel<<<dim3(32, NH, 2), dim3(256), 0, stream>>>(Qb, Kb, Vtb, Ab);

  gemm_nt<0><<<dim3(32, 8), dim3(512), 0, stream>>>(Ab, wob, bo, (float*)d_out, nullptr, M, N, K);
}

// Round 2
// 206.389 us; speedup vs baseline: 1.1700x; 1.1700x over previous
//
#include <hip/hip_runtime.h>
#include <cstdint>
#include <cstddef>

#define S_LEN 2048
#define NH 16
#define HD 64
#define DM 1024
#define WIN 1024

typedef unsigned short u16;
typedef __attribute__((ext_vector_type(8))) short bf16x8;
typedef __attribute__((ext_vector_type(4))) float f32x4;
typedef __attribute__((ext_vector_type(4))) u16 u16x4;
typedef __attribute__((ext_vector_type(2))) uint32_t u32x2;

__device__ inline u16 f2b(float f) {
  union { float f; uint32_t u; } x; x.f = f;
  uint32_t r = x.u + 0x7FFFu + ((x.u >> 16) & 1u);
  return (u16)(r >> 16);
}

__device__ inline uint32_t cvt_pk_bf16(float a, float b) {
  uint32_t r;
  asm("v_cvt_pk_bf16_f32 %0, %1, %2" : "=v"(r) : "v"(a), "v"(b));
  return r;
}

__device__ inline void gload16(const u16* g, u16* l) {
  __builtin_amdgcn_global_load_lds((const __attribute__((address_space(1))) void*)g,
                                   (__attribute__((address_space(3))) void*)l, 16, 0, 0);
}

// ---------------- f32 -> bf16 conversion ----------------
__global__ __launch_bounds__(256) void cvt_kernel(const float* __restrict__ src,
                                                  u16* __restrict__ dst, int n) {
  int i = (blockIdx.x * 256 + threadIdx.x) * 4;
  if (i >= n) return;
  f32x4 v = *(const f32x4*)(src + i);
  u16x4 o;
  o[0] = f2b(v[0]); o[1] = f2b(v[1]); o[2] = f2b(v[2]); o[3] = f2b(v[3]);
  *(u16x4*)(dst + i) = o;
}

// ---------------- bf16 NT GEMM: C = A * B^T + bias ----------------
// A: [M][K] bf16 row-major, B: [N][K] bf16 row-major.
// EPI 0: write f32 to outF[row*N+col], bias b0
// EPI 1: fused QKV: which=col>>10 selects Q/K/V region of outQ, bias b0/b1/b2
template<int EPI>
__global__ __launch_bounds__(512)
void gemm_nt(const u16* __restrict__ A, const u16* __restrict__ B,
             const float* __restrict__ b0, const float* __restrict__ b1,
             const float* __restrict__ b2,
             float* __restrict__ outF, u16* __restrict__ outQ,
             int M, int N, int K) {
  __shared__ u16 As[128 * 32];
  __shared__ u16 Bs[128 * 32];
  const int t = threadIdx.x;
  const int lane = t & 63, wid = t >> 6;
  const int l15 = lane & 15, l4 = lane >> 4;
  const int wr = wid >> 2, wc = wid & 3;        // 2 x 4 wave grid, wave tile 64x32
  const int bm = blockIdx.x * 128, bn = blockIdx.y * 128;
  const int sr = t >> 2, sc = (t & 3) << 3;     // staging: row t/4, col (t%4)*8
  const u16* Ag = A + (size_t)(bm + sr) * K + sc;
  const u16* Bg = B + (size_t)(bn + sr) * K + sc;
  u16* Asl = As + wid * 512;                    // wave-uniform LDS dest (lane*16B auto)
  u16* Bsl = Bs + wid * 512;
  f32x4 acc[4][2];
#pragma unroll
  for (int i = 0; i < 4; i++)
#pragma unroll
    for (int j = 0; j < 2; j++) acc[i][j] = (f32x4){0.f, 0.f, 0.f, 0.f};

  for (int kb = 0; kb < K; kb += 32) {
    __syncthreads();
    gload16(Ag + kb, Asl);
    gload16(Bg + kb, Bsl);
    __syncthreads();
    bf16x8 af[4], bq[2];
#pragma unroll
    for (int mi = 0; mi < 4; mi++)
      af[mi] = *(bf16x8*)&As[(wr * 64 + mi * 16 + l15) * 32 + l4 * 8];
#pragma unroll
    for (int ni = 0; ni < 2; ni++)
      bq[ni] = *(bf16x8*)&Bs[(wc * 32 + ni * 16 + l15) * 32 + l4 * 8];
#pragma unroll
    for (int mi = 0; mi < 4; mi++)
#pragma unroll
      for (int ni = 0; ni < 2; ni++)
        acc[mi][ni] = __builtin_amdgcn_mfma_f32_16x16x32_bf16(af[mi], bq[ni], acc[mi][ni], 0, 0, 0);
  }

  const int cb = bn >> 10;
  const float* bp = (EPI == 0) ? b0 : (cb == 0 ? b0 : (cb == 1 ? b1 : b2));
#pragma unroll
  for (int mi = 0; mi < 4; mi++) {
#pragma unroll
    for (int ni = 0; ni < 2; ni++) {
#pragma unroll
      for (int r = 0; r < 4; r++) {
        int row = bm + wr * 64 + mi * 16 + l4 * 4 + r;
        int col = bn + wc * 32 + ni * 16 + l15;
        float v = acc[mi][ni][r] + bp[col & (DM - 1)];
        if (EPI == 0) {
          outF[(size_t)row * N + col] = v;
        } else {
          int b = row >> 11, s = row & (S_LEN - 1);
          int which = col >> 10, cw = col & (DM - 1);
          int h = cw >> 6, d = cw & (HD - 1);
          outQ[(size_t)which * 4194304 +
               (((size_t)(b * NH + h)) * S_LEN + s) * HD + d] = f2b(v);
        }
      }
    }
  }
}

// ---------------- V transpose: [BH][S][64] -> [BH][64][S] ----------------
__global__ __launch_bounds__(256)
void transpose_v(const u16* __restrict__ V, u16* __restrict__ Vt) {
  const int bh = blockIdx.y;
  const int s0 = blockIdx.x * 64;
  __shared__ u16 tile[64][72];
  const int t = threadIdx.x;
  const u16* src = V + ((size_t)bh * S_LEN + s0) * HD;
#pragma unroll
  for (int i = 0; i < 2; i++) {
    int e = t * 8 + i * 2048;
    int r = e >> 6, c = e & 63;
    *(bf16x8*)&tile[r][c] = *(const bf16x8*)(src + e);
  }
  __syncthreads();
  u16* dst = Vt + (size_t)bh * HD * S_LEN + s0;
#pragma unroll
  for (int i = 0; i < 2; i++) {
    int e = t * 8 + i * 2048;
    int d = e >> 6, s = e & 63;
    bf16x8 tmp;
#pragma unroll
    for (int j = 0; j < 8; j++) tmp[j] = (short)tile[s + j][d];
    *(bf16x8*)&dst[(size_t)d * S_LEN + s] = tmp;
  }
}

// ---------------- sliding-window attention with ALiBi (swapped-operand) -------
// Q,K: [BH][S][64] bf16; Vt: [BH][64][S] bf16; out attn: [B*S][1024] bf16
// Per wave: 16 q rows (q = qw + l15), KVBLK = 64 keys/iter.
// S^T = mfma(K, Q): lane holds S^T[k=kb+16kf+4hi+r][q=qw+l15]  -> softmax lane-local.
// O^T = mfma(V^T, P^T): lane holds O^T[d=16dn+4hi+r][q=qw+l15] -> rescale lane-local.
__global__ __launch_bounds__(256)
void attn_kernel(const u16* __restrict__ Q, const u16* __restrict__ Kg,
                 const u16* __restrict__ Vt, u16* __restrict__ attn) {
  const int bid = blockIdx.x;
  const int job = (bid & 7) * 128 + (bid >> 3);   // XCD swizzle: 4 (b,h) per XCD
  const int bh = job >> 5, qt = job & 31;
  const int b = bh >> 4, h = bh & 15;
  const int t = threadIdx.x;
  const int lane = t & 63, wid = t >> 6;
  const int l15 = lane & 15, hi = lane >> 4;
  const int q0 = qt * 64;
  const int qw = q0 + wid * 16;
  const u16* Qp = Q + (size_t)bh * (S_LEN * HD);
  const u16* Kp = Kg + (size_t)bh * (S_LEN * HD);
  const u16* Vp = Vt + (size_t)bh * (HD * S_LEN);
  __shared__ u16 Pl[4][16 * 80];   // per-wave P buffer, stride 80 (16B-aligned rows)
  u16* Pw = &Pl[wid][0];

  // Q as B-frag (swapped): lane holds Q[qw+l15][32ks + 8hi + i]
  bf16x8 qa[2];
#pragma unroll
  for (int ks = 0; ks < 2; ks++)
    qa[ks] = *(const bf16x8*)(Qp + (size_t)(qw + l15) * HD + ks * 32 + hi * 8);

  const float slope2 = exp2f(-0.5f * (float)(h + 1)) * 1.44269504f;  // log2-domain
  const float qkscale = 0.125f * 1.44269504f;
  const int qrow = qw + l15;
  float m = -3e38f, lsum = 0.f;
  f32x4 O[4];
#pragma unroll
  for (int dn = 0; dn < 4; dn++) O[dn] = (f32x4){0.f, 0.f, 0.f, 0.f};

  int kb_lo = q0 - (WIN - 1);
  if (kb_lo < 0) kb_lo = 0;
  kb_lo &= ~63;

  for (int kb = kb_lo; kb <= q0; kb += 64) {
    // ---- S^T = K . Q^T  (rows k, cols q) ----
    f32x4 st[4];
#pragma unroll
    for (int kf = 0; kf < 4; kf++) {
      st[kf] = (f32x4){0.f, 0.f, 0.f, 0.f};
#pragma unroll
      for (int ks = 0; ks < 2; ks++) {
        bf16x8 ka = *(const bf16x8*)(Kp + (size_t)(kb + 16 * kf + l15) * HD + ks * 32 + hi * 8);
        st[kf] = __builtin_amdgcn_mfma_f32_16x16x32_bf16(ka, qa[ks], st[kf], 0, 0, 0);
      }
    }
    // ---- issue V loads early (consumed after the fence) ----
    bf16x8 va[4][2];
#pragma unroll
    for (int dn = 0; dn < 4; dn++)
#pragma unroll
      for (int ks = 0; ks < 2; ks++)
        va[dn][ks] = *(const bf16x8*)(Vp + (size_t)(dn * 16 + l15) * S_LEN + kb + 32 * ks + 8 * hi);

    // ---- scale + alibi (+ mask only on boundary tiles), log2 domain ----
    float sv[4][4];
    const int kbase = kb + 4 * hi - qrow;
    const bool bdry = (kb + 63 > qw) || (kb < qw - 1008);
    if (bdry) {
#pragma unroll
      for (int kf = 0; kf < 4; kf++)
#pragma unroll
        for (int r = 0; r < 4; r++) {
          int dk = kbase + 16 * kf + r;          // kcol - qrow
          float s = st[kf][r] * qkscale + slope2 * (float)dk;
          sv[kf][r] = (dk > 0 || dk <= -WIN) ? -3e38f : s;
        }
    } else {
#pragma unroll
      for (int kf = 0; kf < 4; kf++)
#pragma unroll
        for (int r = 0; r < 4; r++) {
          int dk = kbase + 16 * kf + r;
          sv[kf][r] = st[kf][r] * qkscale + slope2 * (float)dk;
        }
    }
    // ---- lane-local online softmax (q = l15; only 2+2 shuffles) ----
    float rmax = sv[0][0];
#pragma unroll
    for (int kf = 0; kf < 4; kf++)
#pragma unroll
      for (int r = 0; r < 4; r++) rmax = fmaxf(rmax, sv[kf][r]);
    rmax = fmaxf(rmax, __shfl_xor(rmax, 16, 64));
    rmax = fmaxf(rmax, __shfl_xor(rmax, 32, 64));
    float mn = fmaxf(fmaxf(m, rmax), -1e30f);
    float sc = exp2f(m - mn);
    m = mn;
    float p[4][4], rsum = 0.f;
#pragma unroll
    for (int kf = 0; kf < 4; kf++)
#pragma unroll
      for (int r = 0; r < 4; r++) {
        p[kf][r] = exp2f(sv[kf][r] - m);
        rsum += p[kf][r];
      }
    rsum += __shfl_xor(rsum, 16, 64);
    rsum += __shfl_xor(rsum, 32, 64);
    lsum = lsum * sc + rsum;

    // ---- P^T -> B-frag via per-wave LDS (no block barrier needed) ----
#pragma unroll
    for (int kf = 0; kf < 4; kf++) {
      uint32_t w0 = cvt_pk_bf16(p[kf][0], p[kf][1]);
      uint32_t w1 = cvt_pk_bf16(p[kf][2], p[kf][3]);
      *(uint32_t*)&Pw[l15 * 80 + 16 * kf + 4 * hi] = w0;
      *(uint32_t*)&Pw[l15 * 80 + 16 * kf + 4 * hi + 2] = w1;
    }
    // DS ops from one wave complete in order; only compiler reordering must be
    // blocked, plus lgkmcnt drain for the data return.
    asm volatile("s_waitcnt lgkmcnt(0)" ::: "memory");
    bf16x8 pb[2];
    pb[0] = *(bf16x8*)&Pw[l15 * 80 + 8 * hi];
    pb[1] = *(bf16x8*)&Pw[l15 * 80 + 32 + 8 * hi];

    // ---- rescale O (lane-local), then O^T += V^T . P^T ----
#pragma unroll
    for (int dn = 0; dn < 4; dn++)
#pragma unroll
      for (int r = 0; r < 4; r++) O[dn][r] *= sc;
#pragma unroll
    for (int dn = 0; dn < 4; dn++)
#pragma unroll
      for (int ks = 0; ks < 2; ks++)
        O[dn] = __builtin_amdgcn_mfma_f32_16x16x32_bf16(va[dn][ks], pb[ks], O[dn], 0, 0, 0);
  }

  const float invl = 1.f / lsum;
  u16* op = attn + ((size_t)(b * S_LEN) + qw + l15) * DM + h * HD + 4 * hi;
#pragma unroll
  for (int dn = 0; dn < 4; dn++) {
    u32x2 w;
    w[0] = cvt_pk_bf16(O[dn][0] * invl, O[dn][1] * invl);
    w[1] = cvt_pk_bf16(O[dn][2] * invl, O[dn][3] * invl);
    *(u32x2*)(op + dn * 16) = w;
  }
}

// ---------------- launch ----------------
extern "C" void kernel_launch(void* const* d_in, const int* in_sizes, int n_in,
                              void* d_out, int out_size, void* d_ws, size_t ws_size,
                              hipStream_t stream) {
  const float* x  = (const float*)d_in[0];
  const float* wq = (const float*)d_in[1];
  const float* bq = (const float*)d_in[2];
  const float* wk = (const float*)d_in[3];
  const float* bk = (const float*)d_in[4];
  const float* wv = (const float*)d_in[5];
  const float* bv = (const float*)d_in[6];
  const float* wo = (const float*)d_in[7];
  const float* bo = (const float*)d_in[8];

  char* ws = (char*)d_ws;
  u16* xb    = (u16*)(ws);                  // 8 MB  [4096][1024]
  u16* wqkvb = (u16*)(ws + 8388608);        // 6 MB  [3072][1024]
  u16* wob   = (u16*)(ws + 14680064);       // 2 MB  [1024][1024]
  u16* QKVb  = (u16*)(ws + 16777216);       // 24 MB: Q|K|V each [BH][S][64]
  u16* Vtb   = (u16*)(ws + 41943040);       // 8 MB  [BH][64][S]
  u16* Ab    = (u16*)(ws + 50331648);       // 8 MB  [B*S][1024]
  u16* Vb    = QKVb + 2 * 4194304;

  const int M = 4096;

  cvt_kernel<<<dim3(4096), dim3(256), 0, stream>>>(x, xb, 4194304);
  cvt_kernel<<<dim3(1024), dim3(256), 0, stream>>>(wq, wqkvb,           1048576);
  cvt_kernel<<<dim3(1024), dim3(256), 0, stream>>>(wk, wqkvb + 1048576, 1048576);
  cvt_kernel<<<dim3(1024), dim3(256), 0, stream>>>(wv, wqkvb + 2097152, 1048576);
  cvt_kernel<<<dim3(1024), dim3(256), 0, stream>>>(wo, wob,             1048576);

  gemm_nt<1><<<dim3(32, 24), dim3(512), 0, stream>>>(xb, wqkvb, bq, bk, bv,
                                                     nullptr, QKVb, M, 3072, DM);

  transpose_v<<<dim3(32, 32), dim3(256), 0, stream>>>(Vb, Vtb);

  attn_kernel<<<dim3(1024), dim3(256), 0, stream>>>(QKVb, QKVb + 4194304, Vtb, Ab);

  gemm_nt<0><<<dim3(32, 8), dim3(512), 0, stream>>>(Ab, wob, bo, nullptr, nullptr,
                                                    (float*)d_out, nullptr, M, DM, DM);
}

// Round 4
// 172.946 us; speedup vs baseline: 1.3963x; 1.1934x over previous
//
#include <hip/hip_runtime.h>
#include <cstdint>
#include <cstddef>

#define S_LEN 2048
#define NH 16
#define HD 64
#define DM 1024
#define WIN 1024

typedef unsigned short u16;
typedef __attribute__((ext_vector_type(8))) short bf16x8;
typedef __attribute__((ext_vector_type(4))) short bf16x4;
typedef __attribute__((ext_vector_type(4))) float f32x4;
typedef __attribute__((ext_vector_type(16))) float f32x16;
typedef __attribute__((ext_vector_type(4))) u16 u16x4;
typedef __attribute__((ext_vector_type(4))) uint32_t u32x4;

__device__ inline u16 f2b(float f) {
  union { float f; uint32_t u; } x; x.f = f;
  uint32_t r = x.u + 0x7FFFu + ((x.u >> 16) & 1u);
  return (u16)(r >> 16);
}

__device__ inline uint32_t cvt_pk_bf16(float a, float b) {
  uint32_t r;
  asm("v_cvt_pk_bf16_f32 %0, %1, %2" : "=v"(r) : "v"(a), "v"(b));
  return r;
}

__device__ inline void gload16(const u16* g, u16* l) {
  __builtin_amdgcn_global_load_lds((const __attribute__((address_space(1))) void*)g,
                                   (__attribute__((address_space(3))) void*)l, 16, 0, 0);
}

// ---------------- f32 -> bf16 conversion ----------------
__global__ __launch_bounds__(256) void cvt_kernel(const float* __restrict__ src,
                                                  u16* __restrict__ dst, int n) {
  int i = (blockIdx.x * 256 + threadIdx.x) * 4;
  if (i >= n) return;
  f32x4 v = *(const f32x4*)(src + i);
  u16x4 o;
  o[0] = f2b(v[0]); o[1] = f2b(v[1]); o[2] = f2b(v[2]); o[3] = f2b(v[3]);
  *(u16x4*)(dst + i) = o;
}

// ---------------- bf16 NT GEMM: C = A * B^T + bias ----------------
template<int EPI>
__global__ __launch_bounds__(512)
void gemm_nt(const u16* __restrict__ A, const u16* __restrict__ B,
             const float* __restrict__ b0, const float* __restrict__ b1,
             const float* __restrict__ b2,
             float* __restrict__ outF, u16* __restrict__ outQ,
             int M, int N, int K) {
  __shared__ u16 As[128 * 32];
  __shared__ u16 Bs[128 * 32];
  const int t = threadIdx.x;
  const int lane = t & 63, wid = t >> 6;
  const int l15 = lane & 15, l4 = lane >> 4;
  const int wr = wid >> 2, wc = wid & 3;
  const int bm = blockIdx.x * 128, bn = blockIdx.y * 128;
  const int sr = t >> 2, sc = (t & 3) << 3;
  const u16* Ag = A + (size_t)(bm + sr) * K + sc;
  const u16* Bg = B + (size_t)(bn + sr) * K + sc;
  u16* Asl = As + wid * 512;
  u16* Bsl = Bs + wid * 512;
  f32x4 acc[4][2];
#pragma unroll
  for (int i = 0; i < 4; i++)
#pragma unroll
    for (int j = 0; j < 2; j++) acc[i][j] = (f32x4){0.f, 0.f, 0.f, 0.f};

  for (int kb = 0; kb < K; kb += 32) {
    __syncthreads();
    gload16(Ag + kb, Asl);
    gload16(Bg + kb, Bsl);
    __syncthreads();
    bf16x8 af[4], bq[2];
#pragma unroll
    for (int mi = 0; mi < 4; mi++)
      af[mi] = *(bf16x8*)&As[(wr * 64 + mi * 16 + l15) * 32 + l4 * 8];
#pragma unroll
    for (int ni = 0; ni < 2; ni++)
      bq[ni] = *(bf16x8*)&Bs[(wc * 32 + ni * 16 + l15) * 32 + l4 * 8];
#pragma unroll
    for (int mi = 0; mi < 4; mi++)
#pragma unroll
      for (int ni = 0; ni < 2; ni++)
        acc[mi][ni] = __builtin_amdgcn_mfma_f32_16x16x32_bf16(af[mi], bq[ni], acc[mi][ni], 0, 0, 0);
  }

  const int cb = bn >> 10;
  const float* bp = (EPI == 0) ? b0 : (cb == 0 ? b0 : (cb == 1 ? b1 : b2));
#pragma unroll
  for (int mi = 0; mi < 4; mi++) {
#pragma unroll
    for (int ni = 0; ni < 2; ni++) {
#pragma unroll
      for (int r = 0; r < 4; r++) {
        int row = bm + wr * 64 + mi * 16 + l4 * 4 + r;
        int col = bn + wc * 32 + ni * 16 + l15;
        float v = acc[mi][ni][r] + bp[col & (DM - 1)];
        if (EPI == 0) {
          outF[(size_t)row * N + col] = v;
        } else {
          int b = row >> 11, s = row & (S_LEN - 1);
          int which = col >> 10, cw = col & (DM - 1);
          int h = cw >> 6, d = cw & (HD - 1);
          outQ[(size_t)which * 4194304 +
               (((size_t)(b * NH + h)) * S_LEN + s) * HD + d] = f2b(v);
        }
      }
    }
  }
}

// ---------------- V transpose: [BH][S][64] -> [BH][64][S] ----------------
__global__ __launch_bounds__(256)
void transpose_v(const u16* __restrict__ V, u16* __restrict__ Vt) {
  const int bh = blockIdx.y;
  const int s0 = blockIdx.x * 64;
  __shared__ u16 tile[64][72];
  const int t = threadIdx.x;
  const u16* src = V + ((size_t)bh * S_LEN + s0) * HD;
#pragma unroll
  for (int i = 0; i < 2; i++) {
    int e = t * 8 + i * 2048;
    int r = e >> 6, c = e & 63;
    *(bf16x8*)&tile[r][c] = *(const bf16x8*)(src + e);
  }
  __syncthreads();
  u16* dst = Vt + (size_t)bh * HD * S_LEN + s0;
#pragma unroll
  for (int i = 0; i < 2; i++) {
    int e = t * 8 + i * 2048;
    int d = e >> 6, s = e & 63;
    bf16x8 tmp;
#pragma unroll
    for (int j = 0; j < 8; j++) tmp[j] = (short)tile[s + j][d];
    *(bf16x8*)&dst[(size_t)d * S_LEN + s] = tmp;
  }
}

// ---------------- attention: 32x32 MFMA, lane-local softmax, no permlane ----
// Per wave (1 wave/block): 32 q rows, 64-key tiles.
// S^T = mfma(K,Q): lane(l31,hi) holds S^T[k=kb+32s+(r&3)+8(r>>2)+4hi][q=qw+l31].
// PV chunk ks uses slot map sigma(hi,i)=(i&3)+8*(i>>2)+4hi (bijective over [0,16)
// across the two lane halves): P B-frag = own regs packed; V A-frag loaded with
// the same sigma (two 8B loads). Identical sigma on A and B cancels -> correct
// regardless of the HW slot->k mapping; zero cross-lane ops in the P path.
struct KTile { bf16x8 f[2][4]; };

__device__ __forceinline__ KTile loadK(const u16* __restrict__ Kp, int kb, int l31, int hi) {
  KTile k;
#pragma unroll
  for (int s = 0; s < 2; s++)
#pragma unroll
    for (int f = 0; f < 4; f++)
      k.f[s][f] = *(const bf16x8*)(Kp + (size_t)(kb + 32 * s + l31) * HD + 16 * f + 8 * hi);
  return k;
}

__device__ __forceinline__ bf16x8 vfrag(const u16* __restrict__ base) {
  bf16x4 a = *(const bf16x4*)base;        // sigma slots 0..3: keys +4hi+0..3
  bf16x4 b = *(const bf16x4*)(base + 8);  // sigma slots 4..7: keys +8+4hi+0..3
  bf16x8 v;
  v[0] = a[0]; v[1] = a[1]; v[2] = a[2]; v[3] = a[3];
  v[4] = b[0]; v[5] = b[1]; v[6] = b[2]; v[7] = b[3];
  return v;
}

__device__ __forceinline__ void process_tile(
    int kb, const KTile& kt, const u16* __restrict__ Vp, const bf16x8 qf[4],
    int qw, int l31, int hi, float slope2,
    float& m, float& lsum, f32x16& O0, f32x16& O1) {
  // V loads issued first (consumed after softmax)
  bf16x8 vf[2][4];
#pragma unroll
  for (int d = 0; d < 2; d++)
#pragma unroll
    for (int ks = 0; ks < 4; ks++)
      vf[d][ks] = vfrag(Vp + (size_t)(32 * d + l31) * S_LEN + kb + 16 * ks + 4 * hi);

  f32x16 st0, st1;
#pragma unroll
  for (int r = 0; r < 16; r++) { st0[r] = 0.f; st1[r] = 0.f; }
#pragma unroll
  for (int f = 0; f < 4; f++) {
    st0 = __builtin_amdgcn_mfma_f32_32x32x16_bf16(kt.f[0][f], qf[f], st0, 0, 0, 0);
    st1 = __builtin_amdgcn_mfma_f32_32x32x16_bf16(kt.f[1][f], qf[f], st1, 0, 0, 0);
  }

  const float qks = 0.125f * 1.44269504f;
  const int dkb = kb + 4 * hi - (qw + l31);
  const bool interior = (kb + 63 <= qw) && (kb >= qw - (WIN - 32));
  float p0[16], p1[16];
#pragma unroll
  for (int r = 0; r < 16; r++) {
    int off = (r & 3) + 8 * (r >> 2);
    int dk0 = dkb + off, dk1 = dkb + 32 + off;
    float s0 = st0[r] * qks + slope2 * (float)dk0;
    float s1 = st1[r] * qks + slope2 * (float)dk1;
    if (!interior) {
      s0 = (dk0 > 0 || dk0 <= -WIN) ? -3e38f : s0;
      s1 = (dk1 > 0 || dk1 <= -WIN) ? -3e38f : s1;
    }
    p0[r] = s0; p1[r] = s1;
  }
  // ---- row max: in-register tree + one cross-half shuffle ----
  float t8[8];
#pragma unroll
  for (int r = 0; r < 8; r++)
    t8[r] = fmaxf(fmaxf(p0[r], p0[r + 8]), fmaxf(p1[r], p1[r + 8]));
#pragma unroll
  for (int r = 0; r < 4; r++) t8[r] = fmaxf(t8[r], t8[r + 4]);
  float rmax = fmaxf(fmaxf(t8[0], t8[1]), fmaxf(t8[2], t8[3]));
  rmax = fmaxf(rmax, __shfl_xor(rmax, 32, 64));
  float mn = fmaxf(fmaxf(m, rmax), -1e30f);
  float sc = exp2f(m - mn);
  m = mn;
  // ---- exp + row sum ----
#pragma unroll
  for (int r = 0; r < 16; r++) {
    p0[r] = exp2f(p0[r] - mn);
    p1[r] = exp2f(p1[r] - mn);
  }
  float a8[8];
#pragma unroll
  for (int r = 0; r < 8; r++)
    a8[r] = (p0[r] + p0[r + 8]) + (p1[r] + p1[r + 8]);
#pragma unroll
  for (int r = 0; r < 4; r++) a8[r] += a8[r + 4];
  float rsum = (a8[0] + a8[1]) + (a8[2] + a8[3]);
  rsum += __shfl_xor(rsum, 32, 64);
  lsum = lsum * sc + rsum;

  // ---- P B-frags: own regs packed, chunk ks <- regs 8*(ks&1)..+7 of p[ks>>1] ----
  auto pk8 = [&](const float (&pp)[16], int base) -> bf16x8 {
    u32x4 w4;
    w4[0] = cvt_pk_bf16(pp[base + 0], pp[base + 1]);
    w4[1] = cvt_pk_bf16(pp[base + 2], pp[base + 3]);
    w4[2] = cvt_pk_bf16(pp[base + 4], pp[base + 5]);
    w4[3] = cvt_pk_bf16(pp[base + 6], pp[base + 7]);
    return __builtin_bit_cast(bf16x8, w4);
  };
  bf16x8 pb[4];
  pb[0] = pk8(p0, 0); pb[1] = pk8(p0, 8);
  pb[2] = pk8(p1, 0); pb[3] = pk8(p1, 8);

  // ---- rescale O, then O^T += V^T . P^T ----
#pragma unroll
  for (int r = 0; r < 16; r++) { O0[r] *= sc; O1[r] *= sc; }
#pragma unroll
  for (int ks = 0; ks < 4; ks++) {
    O0 = __builtin_amdgcn_mfma_f32_32x32x16_bf16(vf[0][ks], pb[ks], O0, 0, 0, 0);
    O1 = __builtin_amdgcn_mfma_f32_32x32x16_bf16(vf[1][ks], pb[ks], O1, 0, 0, 0);
  }
}

__global__ __launch_bounds__(64, 1)
void attn_kernel(const u16* __restrict__ Q, const u16* __restrict__ Kg,
                 const u16* __restrict__ Vt, u16* __restrict__ attn) {
  const int bid = blockIdx.x;
  const int job = (bid & 7) * 256 + (bid >> 3);  // XCD swizzle (2048 % 8 == 0)
  const int bh = job >> 6, qt = job & 63;
  const int b = bh >> 4, h = bh & 15;
  const int lane = threadIdx.x;
  const int l31 = lane & 31, hi = lane >> 5;
  const int qw = qt * 32;
  const u16* Qp = Q + (size_t)bh * (S_LEN * HD);
  const u16* Kp = Kg + (size_t)bh * (S_LEN * HD);
  const u16* Vp = Vt + (size_t)bh * (HD * S_LEN);

  bf16x8 qf[4];
#pragma unroll
  for (int f = 0; f < 4; f++)
    qf[f] = *(const bf16x8*)(Qp + (size_t)(qw + l31) * HD + 16 * f + 8 * hi);

  const float slope2 = exp2f(-0.5f * (float)(h + 1)) * 1.44269504f;
  float m = -3e38f, lsum = 0.f;
  f32x16 O0, O1;
#pragma unroll
  for (int r = 0; r < 16; r++) { O0[r] = 0.f; O1[r] = 0.f; }

  int lo = qw - (WIN - 1); if (lo < 0) lo = 0; lo &= ~63;
  const int last = (qw + 31) & ~63;

  KTile ka = loadK(Kp, lo, l31, hi);
  int kb = lo;
  for (;;) {
    int kb1 = kb + 64; bool h1 = kb1 <= last;
    KTile kbt = loadK(Kp, h1 ? kb1 : kb, l31, hi);
    process_tile(kb, ka, Vp, qf, qw, l31, hi, slope2, m, lsum, O0, O1);
    if (!h1) break;
    int kb2 = kb + 128; bool h2 = kb2 <= last;
    ka = loadK(Kp, h2 ? kb2 : kb1, l31, hi);
    process_tile(kb1, kbt, Vp, qf, qw, l31, hi, slope2, m, lsum, O0, O1);
    if (!h2) break;
    kb = kb2;
  }

  const float invl = 1.f / lsum;
  u16* op = attn + ((size_t)(b * S_LEN) + qw + l31) * DM + h * HD;
#pragma unroll
  for (int r = 0; r < 16; r += 2) {
    int d0 = (r & 3) + 8 * (r >> 2) + 4 * hi;
    uint32_t w0 = cvt_pk_bf16(O0[r] * invl, O0[r + 1] * invl);
    uint32_t w1 = cvt_pk_bf16(O1[r] * invl, O1[r + 1] * invl);
    *(uint32_t*)(op + d0) = w0;
    *(uint32_t*)(op + 32 + d0) = w1;
  }
}

// ---------------- launch ----------------
extern "C" void kernel_launch(void* const* d_in, const int* in_sizes, int n_in,
                              void* d_out, int out_size, void* d_ws, size_t ws_size,
                              hipStream_t stream) {
  const float* x  = (const float*)d_in[0];
  const float* wq = (const float*)d_in[1];
  const float* bq = (const float*)d_in[2];
  const float* wk = (const float*)d_in[3];
  const float* bk = (const float*)d_in[4];
  const float* wv = (const float*)d_in[5];
  const float* bv = (const float*)d_in[6];
  const float* wo = (const float*)d_in[7];
  const float* bo = (const float*)d_in[8];

  char* ws = (char*)d_ws;
  u16* xb    = (u16*)(ws);                  // 8 MB  [4096][1024]
  u16* wqkvb = (u16*)(ws + 8388608);        // 6 MB  [3072][1024]
  u16* wob   = (u16*)(ws + 14680064);       // 2 MB  [1024][1024]
  u16* QKVb  = (u16*)(ws + 16777216);       // 24 MB: Q|K|V each [BH][S][64]
  u16* Vtb   = (u16*)(ws + 41943040);       // 8 MB  [BH][64][S]
  u16* Ab    = (u16*)(ws + 50331648);       // 8 MB  [B*S][1024]
  u16* Vb    = QKVb + 2 * 4194304;

  const int M = 4096;

  cvt_kernel<<<dim3(4096), dim3(256), 0, stream>>>(x, xb, 4194304);
  cvt_kernel<<<dim3(1024), dim3(256), 0, stream>>>(wq, wqkvb,           1048576);
  cvt_kernel<<<dim3(1024), dim3(256), 0, stream>>>(wk, wqkvb + 1048576, 1048576);
  cvt_kernel<<<dim3(1024), dim3(256), 0, stream>>>(wv, wqkvb + 2097152, 1048576);
  cvt_kernel<<<dim3(1024), dim3(256), 0, stream>>>(wo, wob,             1048576);

  gemm_nt<1><<<dim3(32, 24), dim3(512), 0, stream>>>(xb, wqkvb, bq, bk, bv,
                                                     nullptr, QKVb, M, 3072, DM);

  transpose_v<<<dim3(32, 32), dim3(256), 0, stream>>>(Vb, Vtb);

  attn_kernel<<<dim3(2048), dim3(64), 0, stream>>>(QKVb, QKVb + 4194304, Vtb, Ab);

  gemm_nt<0><<<dim3(32, 8), dim3(512), 0, stream>>>(Ab, wob, bo, nullptr, nullptr,
                                                    (float*)d_out, nullptr, M, DM, DM);
}